// Round 6
// baseline (284.432 us; speedup 1.0000x reference)
//
#include <hip/hip_runtime.h>

#define B_   32
#define E_   512
#define HW_  256
#define S_   257
#define NH_  8
#define HD_  64
#define ECH_ 8           // e per chunk in P3
#define NCH_ 64          // chunks per batch
#define NBLK 2048
#define NTHR 256
#define NGRP 32
#define GSZ  64

// write-through stores (sc0 sc1): land at the coherence point (L3). Intermediates
// are written once and first-read only after a barrier, so no reader L2 can hold
// a stale copy -> barriers need zero cache-maintenance ops (round-3/4/5-verified).
__device__ __forceinline__ void st_sys(float* p, float v) {
  __hip_atomic_store(p, v, __ATOMIC_RELAXED, __HIP_MEMORY_SCOPE_SYSTEM);
}
__device__ __forceinline__ void st_sys2(float2* p, float2 v) {
  unsigned long long u;
  __builtin_memcpy(&u, &v, 8);
  __hip_atomic_store((unsigned long long*)p, u, __ATOMIC_RELAXED, __HIP_MEMORY_SCOPE_SYSTEM);
}

__device__ __forceinline__ float wave_reduce(float v) {
  #pragma unroll
  for (int o = 32; o > 0; o >>= 1) v += __shfl_down(v, o, 64);
  return v;
}

// Group-local barrier (64 blocks of one batch). Block j write-through-stores its
// monotone phase number into word j of the group's 256-B slot region; wave 0
// polls all 64 slots (one per lane) with system-scope relaxed loads (always
// served from the coherence point -> cannot spin stale). Verified R3-R5.
__device__ __forceinline__ void gbar(unsigned* slots, int g, int j, int t, unsigned phase) {
  __syncthreads();                        // drains vmcnt: all data stores acked
  if (t < 64) {
    if (t == 0)
      __hip_atomic_store(&slots[g * GSZ + j], phase, __ATOMIC_RELAXED, __HIP_MEMORY_SCOPE_SYSTEM);
    const unsigned* line = slots + g * GSZ;
    for (;;) {
      unsigned v = __hip_atomic_load(&line[t], __ATOMIC_RELAXED, __HIP_MEMORY_SCOPE_SYSTEM);
      if (__all((int)(v >= phase))) break;
      __builtin_amdgcn_s_sleep(2);
    }
  }
  __syncthreads();
}

// Wave-shuffle softmax: 3 __syncthreads (verified R5).
__device__ void softmax257(float* l, float* red, int t) {
  int lane = t & 63, wv = t >> 6;
  float v = l[t];
  float v256 = l[256];
  float m = v;
  #pragma unroll
  for (int o = 32; o > 0; o >>= 1) m = fmaxf(m, __shfl_xor(m, o, 64));
  if (lane == 0) red[wv] = m;
  __syncthreads();
  float M = fmaxf(fmaxf(fmaxf(red[0], red[1]), fmaxf(red[2], red[3])), v256);
  float ex = expf(v - M);
  float e256 = expf(v256 - M);
  float s = ex;
  #pragma unroll
  for (int o = 32; o > 0; o >>= 1) s += __shfl_xor(s, o, 64);
  if (lane == 0) red[4 + wv] = s;
  __syncthreads();
  float inv = 1.f / (red[4] + red[5] + red[6] + red[7] + e256);
  l[t] = ex * inv;
  if (t == 0) l[256] = e256 * inv;
  __syncthreads();
}

__global__ __launch_bounds__(NTHR, 8) void k_mega(
    const float* __restrict__ xr, const float* __restrict__ xi,
    const float* __restrict__ pos_r, const float* __restrict__ pos_i,
    const float* __restrict__ w_in_r, const float* __restrict__ w_in_i,
    const float* __restrict__ b_in_r, const float* __restrict__ b_in_i,
    const float* __restrict__ w_out_r, const float* __restrict__ w_out_i,
    const float* __restrict__ b_out_r, const float* __restrict__ b_out_i,
    const float* __restrict__ w_p_r, const float* __restrict__ w_p_i,
    const float* __restrict__ b_p_r, const float* __restrict__ b_p_i,
    unsigned* slots,
    float* __restrict__ mr, float* __restrict__ mi,
    float* __restrict__ q0r, float* __restrict__ q0i,
    float* __restrict__ l0pr, float* __restrict__ l0pi,
    float* __restrict__ part, float* __restrict__ w2,
    float* __restrict__ zr_, float* __restrict__ zi_,
    float* __restrict__ a0r, float* __restrict__ a0i,
    float* __restrict__ aor, float* __restrict__ aoi,
    float* __restrict__ out, int interleaved) {
  __shared__ __align__(16) float smF[4112];   // max phase: P5's 2056 float2 = 16448 B
  const int t   = threadIdx.x;
  const int l   = t & 63;
  const int w   = t >> 6;
  const int bid = blockIdx.x;
  const int g   = bid >> 6;     // batch b (32 groups)
  const int j   = bid & 63;     // block within group (64 blocks/group)

  // ---- P1: m[g,e] = mean_s x + pos[e,0]. Block j owns e rows [8j, 8j+8);
  //      each wave does 2 rows, one float4/lane = one 256-float row. ----
  #pragma unroll
  for (int rr = 0; rr < 2; ++rr) {
    int e = j * 8 + w * 2 + rr;
    float4 vr = ((const float4*)(xr + ((size_t)g * E_ + e) * HW_))[l];
    float4 vi = ((const float4*)(xi + ((size_t)g * E_ + e) * HW_))[l];
    float sr = (vr.x + vr.y) + (vr.z + vr.w);
    float si = (vi.x + vi.y) + (vi.z + vi.w);
    sr = wave_reduce(sr); si = wave_reduce(si);
    if (l == 0) {
      st_sys(&mr[g * E_ + e], sr * (1.f / HW_) + pos_r[(size_t)e * S_]);
      st_sys(&mi[g * E_ + e], si * (1.f / HW_) + pos_i[(size_t)e * S_]);
    }
  }
  gbar(slots, g, j, t, 1);

  // ---- P2: q0[g,f] = (m[g,:] . w_q[f,:] + b_q[f])/8. Block j owns 8 f-rows. ----
  {
    float* mR = smF;          // 512
    float* mI = smF + 512;    // 512
    mR[t]       = mr[g * E_ + t];        mI[t]       = mi[g * E_ + t];
    mR[t + 256] = mr[g * E_ + t + 256];  mI[t + 256] = mi[g * E_ + t + 256];
    __syncthreads();
    #pragma unroll
    for (int rr = 0; rr < 2; ++rr) {
      int f = j * 8 + w * 2 + rr;
      const float* wr = w_in_r + (size_t)f * E_;
      const float* wi = w_in_i + (size_t)f * E_;
      float ar = 0.f, ai = 0.f;
      #pragma unroll
      for (int e = l; e < E_; e += 64) {
        float Xr = mR[e], Xi = mI[e], Cr = wr[e], Ci = wi[e];
        ar += Xr * Cr - Xi * Ci;
        ai += Xr * Ci + Xi * Cr;
      }
      ar = wave_reduce(ar); ai = wave_reduce(ai);
      if (l == 0) {
        st_sys(&q0r[g * E_ + f], (ar + b_in_r[f]) * 0.125f);
        st_sys(&q0i[g * E_ + f], (ai + b_in_i[f]) * 0.125f);
      }
    }
  }
  gbar(slots, g, j, t, 2);

  // ---- P3: per e-chunk c=j (8 e): u[h,e] in-LDS (all 256 threads via d-quarter
  //      split), l0 chunk-partials, partial logits for all 8 heads. ----
  {
    int c = j, e0 = c * ECH_;
    float* q0s = smF;            // 1024: [f]*2+ri
    float* us  = smF + 1024;     // 128:  [(e*8+h)*2+ri]
    float* pu  = smF + 1152;     // 512:  [(dq*64 + e*8 + h)*2+ri]
    float* mS  = smF + 1664;     // 16:   [e]*2+ri
    { int f0 = t * 2;
      q0s[f0 * 2 + 0]       = q0r[g * E_ + f0];
      q0s[f0 * 2 + 1]       = q0i[g * E_ + f0];
      q0s[(f0 + 1) * 2 + 0] = q0r[g * E_ + f0 + 1];
      q0s[(f0 + 1) * 2 + 1] = q0i[g * E_ + f0 + 1];
      if (t < ECH_) { mS[t * 2] = mr[g * E_ + e0 + t]; mS[t * 2 + 1] = mi[g * E_ + e0 + t]; }
    }
    __syncthreads();
    {   // u partials: e = t&7, h = (t>>3)&7, d-quarter = t>>6
      int e = t & 7, hh = (t >> 3) & 7, dq = t >> 6;
      float ar = 0.f, ai = 0.f;
      #pragma unroll
      for (int dd = 0; dd < 16; ++dd) {
        int f = hh * HD_ + dq * 16 + dd;
        float qr = q0s[f * 2], qi = q0s[f * 2 + 1];
        float Wr = w_in_r[(size_t)(E_ + f) * E_ + e0 + e];
        float Wi = w_in_i[(size_t)(E_ + f) * E_ + e0 + e];
        ar += qr * Wr - qi * Wi;
        ai += qr * Wi + qi * Wr;
      }
      pu[(dq * 64 + e * 8 + hh) * 2 + 0] = ar;
      pu[(dq * 64 + e * 8 + hh) * 2 + 1] = ai;
    }
    __syncthreads();
    if (t < 128) {
      int e = t & 7, hh = (t >> 3) & 7, ri = t >> 6;
      us[(e * 8 + hh) * 2 + ri] =
          pu[(0 * 64 + e * 8 + hh) * 2 + ri] + pu[(1 * 64 + e * 8 + hh) * 2 + ri] +
          pu[(2 * 64 + e * 8 + hh) * 2 + ri] + pu[(3 * 64 + e * 8 + hh) * 2 + ri];
    }
    __syncthreads();
    if (t < NH_) {                         // l0 chunk-partial for head t
      float pr = 0.f, pi = 0.f;
      #pragma unroll
      for (int e = 0; e < ECH_; ++e) {
        float Xr = mS[e * 2], Xi = mS[e * 2 + 1];
        float Ur = us[(e * 8 + t) * 2], Ui = us[(e * 8 + t) * 2 + 1];
        pr += Xr * Ur - Xi * Ui;
        pi += Xr * Ui + Xi * Ur;
      }
      st_sys(&l0pr[((size_t)g * NH_ + t) * NCH_ + c], pr);
      st_sys(&l0pi[((size_t)g * NH_ + t) * NCH_ + c], pi);
    }
    float ar[NH_], ai[NH_];
    #pragma unroll
    for (int hh = 0; hh < NH_; ++hh) { ar[hh] = 0.f; ai[hh] = 0.f; }
    const float* xrb = xr + ((size_t)g * E_ + e0) * HW_;
    const float* xib = xi + ((size_t)g * E_ + e0) * HW_;
    #pragma unroll 2
    for (int e = 0; e < ECH_; ++e) {
      float Xr = xrb[e * HW_ + t] + pos_r[(size_t)(e0 + e) * S_ + t + 1];
      float Xi = xib[e * HW_ + t] + pos_i[(size_t)(e0 + e) * S_ + t + 1];
      #pragma unroll
      for (int hh = 0; hh < NH_; ++hh) {
        float Ur = us[(e * 8 + hh) * 2], Ui = us[(e * 8 + hh) * 2 + 1];
        ar[hh] += Xr * Ur - Xi * Ui;
        ai[hh] += Xr * Ui + Xi * Ur;
      }
    }
    float2* p2 = (float2*)part;
    #pragma unroll
    for (int hh = 0; hh < NH_; ++hh) {
      float2 v; v.x = ar[hh]; v.y = ai[hh];
      st_sys2(&p2[(((size_t)g * NH_ + hh) * NCH_ + c) * 256 + t], v);
    }
  }
  gbar(slots, g, j, t, 3);

  // ---- P4: blocks j<8 (head j): reduce chunk partials + l0 + dual softmax ----
  if (j < NH_) {
    int bh = g * NH_ + j;
    float* lr  = smF;          // 257
    float* li  = smF + 260;    // 257
    float* red = smF + 520;    // 8
    const float2* p2 = (const float2*)part + (size_t)bh * NCH_ * 256;
    float sr = 0.f, si = 0.f;
    #pragma unroll 8
    for (int c = 0; c < NCH_; ++c) { float2 v = p2[c * 256 + t]; sr += v.x; si += v.y; }
    lr[t + 1] = sr; li[t + 1] = si;
    if (t < 64) {                          // wave 0: real l0 reduce (64 partials)
      float v = l0pr[(size_t)bh * NCH_ + t];
      v = wave_reduce(v);
      if (t == 0) lr[0] = v;
    } else if (t < 128) {                  // wave 1: imag l0 reduce
      int tt = t - 64;
      float v = l0pi[(size_t)bh * NCH_ + tt];
      v = wave_reduce(v);
      if (tt == 0) li[0] = v;
    }
    __syncthreads();
    softmax257(lr, red, t);
    softmax257(li, red, t);
    float2* o = (float2*)w2 + (size_t)bh * S_;
    float2 v; v.x = lr[t]; v.y = li[t];
    st_sys2(&o[t], v);
    if (t == 0) { float2 v2; v2.x = lr[256]; v2.y = li[256]; st_sys2(&o[256], v2); }
  }
  gbar(slots, g, j, t, 4);

  // ---- P5: z[g,h,e] = sum_k w[g,h,k] X[g,k,e]; block j owns e rows [8j,8j+8)
  //      (same x rows as P1/P3 -> L3-warm); w-tile in LDS. ----
  {
    float2* wls = (float2*)smF;                 // 2056 float2
    const float2* w2b = (const float2*)w2 + (size_t)g * NH_ * S_;
    for (int i = t; i < NH_ * S_; i += NTHR) wls[i] = w2b[i];
    __syncthreads();
    #pragma unroll
    for (int rr = 0; rr < 2; ++rr) {
      int e = 8 * j + 2 * w + rr;
      const float* xre = xr + ((size_t)g * E_ + e) * HW_;
      const float* xie = xi + ((size_t)g * E_ + e) * HW_;
      const float* pre = pos_r + (size_t)e * S_;
      const float* pie = pos_i + (size_t)e * S_;
      float ar2[NH_], ai2[NH_];
      #pragma unroll
      for (int hh = 0; hh < NH_; ++hh) { ar2[hh] = 0.f; ai2[hh] = 0.f; }
      #pragma unroll
      for (int jj = 0; jj < 4; ++jj) {
        int k = 1 + l + 64 * jj;
        float Xr = xre[k - 1] + pre[k];
        float Xi = xie[k - 1] + pie[k];
        #pragma unroll
        for (int hh = 0; hh < NH_; ++hh) {
          float2 W = wls[hh * S_ + k];
          ar2[hh] += W.x * Xr - W.y * Xi;
          ai2[hh] += W.x * Xi + W.y * Xr;
        }
      }
      #pragma unroll
      for (int hh = 0; hh < NH_; ++hh) { ar2[hh] = wave_reduce(ar2[hh]); ai2[hh] = wave_reduce(ai2[hh]); }
      if (l == 0) {
        float X0r = mr[g * E_ + e];
        float X0i = mi[g * E_ + e];
        #pragma unroll
        for (int hh = 0; hh < NH_; ++hh) {
          float2 W0 = wls[hh * S_];
          st_sys(&zr_[(size_t)(g * NH_ + hh) * E_ + e], ar2[hh] + W0.x * X0r - W0.y * X0i);
          st_sys(&zi_[(size_t)(g * NH_ + hh) * E_ + e], ai2[hh] + W0.x * X0i + W0.y * X0r);
        }
      }
    }
  }
  gbar(slots, g, j, t, 5);

  // ---- P6: a0[g,f] = w_v[f,:] . z[g,h(f),:] + b_v[f]*(1+i); block owns 8 f ----
  #pragma unroll
  for (int rr = 0; rr < 2; ++rr) {
    int f = j * 8 + w * 2 + rr;
    int h = f >> 6;
    const float* wrp = w_in_r + (size_t)(2 * E_ + f) * E_;
    const float* wip = w_in_i + (size_t)(2 * E_ + f) * E_;
    const float* zrp = zr_ + (size_t)(g * NH_ + h) * E_;
    const float* zip = zi_ + (size_t)(g * NH_ + h) * E_;
    float ar = 0.f, ai = 0.f;
    #pragma unroll
    for (int e = l; e < E_; e += 64) {
      float Zr = zrp[e], Zi = zip[e], Cr = wrp[e], Ci = wip[e];
      ar += Zr * Cr - Zi * Ci;
      ai += Zr * Ci + Zi * Cr;
    }
    ar = wave_reduce(ar); ai = wave_reduce(ai);
    if (l == 0) {
      float bvr = b_in_r[2 * E_ + f], bvi = b_in_i[2 * E_ + f];
      st_sys(&a0r[g * E_ + f], ar + (bvr - bvi));   // sum of complex softmax weights = 1+i
      st_sys(&a0i[g * E_ + f], ai + (bvr + bvi));
    }
  }
  gbar(slots, g, j, t, 6);

  // ---- P7: ao[g,f] = a0[g,:] . w_out[f,:] + b_out[f] ----
  #pragma unroll
  for (int rr = 0; rr < 2; ++rr) {
    int f = j * 8 + w * 2 + rr;
    const float* wrp = w_out_r + (size_t)f * E_;
    const float* wip = w_out_i + (size_t)f * E_;
    const float* ir = a0r + (size_t)g * E_;
    const float* ii = a0i + (size_t)g * E_;
    float ar = 0.f, ai = 0.f;
    #pragma unroll
    for (int e = l; e < E_; e += 64) {
      float Xr = ir[e], Xi = ii[e], Cr = wrp[e], Ci = wip[e];
      ar += Xr * Cr - Xi * Ci;
      ai += Xr * Ci + Xi * Cr;
    }
    ar = wave_reduce(ar); ai = wave_reduce(ai);
    if (l == 0) { st_sys(&aor[g * E_ + f], ar + b_out_r[f]); st_sys(&aoi[g * E_ + f], ai + b_out_i[f]); }
  }
  gbar(slots, g, j, t, 7);

  // ---- P8: final projection, interleaved complex64 out ----
  #pragma unroll
  for (int rr = 0; rr < 2; ++rr) {
    int f = j * 8 + w * 2 + rr;
    const float* wrp = w_p_r + (size_t)f * E_;
    const float* wip = w_p_i + (size_t)f * E_;
    const float* ir = aor + (size_t)g * E_;
    const float* ii = aoi + (size_t)g * E_;
    float ar = 0.f, ai = 0.f;
    #pragma unroll
    for (int e = l; e < E_; e += 64) {
      float Xr = ir[e], Xi = ii[e], Cr = wrp[e], Ci = wip[e];
      ar += Xr * Cr - Xi * Ci;
      ai += Xr * Ci + Xi * Cr;
    }
    ar = wave_reduce(ar); ai = wave_reduce(ai);
    if (l == 0) {
      float rr2 = ar + b_p_r[f];
      float im  = ai + b_p_i[f];
      int wid = g * E_ + f;
      if (interleaved) { out[(size_t)wid * 2] = rr2; out[(size_t)wid * 2 + 1] = im; }
      else             { out[wid] = rr2; }
    }
  }
}

extern "C" void kernel_launch(void* const* d_in, const int* in_sizes, int n_in,
                              void* d_out, int out_size, void* d_ws, size_t ws_size,
                              hipStream_t stream) {
  (void)in_sizes; (void)n_in; (void)ws_size;
  const float* xr      = (const float*)d_in[0];
  const float* xi      = (const float*)d_in[1];
  const float* pos_r   = (const float*)d_in[2];
  const float* pos_i   = (const float*)d_in[3];
  const float* w_in_r  = (const float*)d_in[4];
  const float* w_in_i  = (const float*)d_in[5];
  const float* b_in_r  = (const float*)d_in[6];
  const float* b_in_i  = (const float*)d_in[7];
  const float* w_out_r = (const float*)d_in[8];
  const float* w_out_i = (const float*)d_in[9];
  const float* b_out_r = (const float*)d_in[10];
  const float* b_out_i = (const float*)d_in[11];
  const float* w_p_r   = (const float*)d_in[12];
  const float* w_p_i   = (const float*)d_in[13];
  const float* b_p_r   = (const float*)d_in[14];
  const float* b_p_i   = (const float*)d_in[15];

  const int BE = B_ * E_, BHE = B_ * NH_ * E_;
  unsigned* slots = (unsigned*)d_ws;             // 32 groups x 64 slots = 8 KB
  float* base = (float*)d_ws + 4096;             // data region at +16 KB
  float* mr   = base;
  float* mi   = mr   + BE;
  float* q0r  = mi   + BE;
  float* q0i  = q0r  + BE;
  float* l0pr = q0i  + BE;                       // B*NH*NCH = 16384
  float* l0pi = l0pr + B_ * NH_ * NCH_;
  float* part = l0pi + B_ * NH_ * NCH_;          // B*NH*NCH*256*2 floats (33.5 MB)
  float* w2   = part + (size_t)B_ * NH_ * NCH_ * 512;
  float* zr   = w2   + (size_t)2 * B_ * NH_ * S_;
  float* zi   = zr   + BHE;
  float* a0r  = zi   + BHE;
  float* a0i  = a0r  + BE;
  float* aor  = a0i  + BE;
  float* aoi  = aor  + BE;

  // ws is re-poisoned every iteration -> zero the barrier slots in-graph; the
  // memset's dispatch-end writeback-invalidate also clears stale L2 lines.
  hipMemsetAsync(d_ws, 0, 16384, stream);
  k_mega<<<NBLK, NTHR, 0, stream>>>(
      xr, xi, pos_r, pos_i, w_in_r, w_in_i, b_in_r, b_in_i,
      w_out_r, w_out_i, b_out_r, b_out_i, w_p_r, w_p_i, b_p_r, b_p_i,
      slots, mr, mi, q0r, q0i, l0pr, l0pi, part, w2, zr, zi, a0r, a0i, aor, aoi,
      (float*)d_out, out_size >= 2 * B_ * E_);
}

// Round 7
// 204.601 us; speedup vs baseline: 1.3902x; 1.3902x over previous
//
#include <hip/hip_runtime.h>

#define B_   32
#define E_   512
#define HW_  256
#define S_   257
#define NH_  8
#define NBLK 1024
#define NTHR 256
#define NGRP 32
#define GSZ  32
#define LG_  260   // padded logit row stride

// write-through stores (sc0 sc1): land at the coherence point (MALL). Intermediates
// are written once and first-read only after a barrier, so no reader L2 can hold
// a stale copy -> barriers need zero cache-maintenance ops (verified R3-R6).
__device__ __forceinline__ void st_sys(float* p, float v) {
  __hip_atomic_store(p, v, __ATOMIC_RELAXED, __HIP_MEMORY_SCOPE_SYSTEM);
}
__device__ __forceinline__ void st_sys2(float2* p, float2 v) {
  unsigned long long u;
  __builtin_memcpy(&u, &v, 8);
  __hip_atomic_store((unsigned long long*)p, u, __ATOMIC_RELAXED, __HIP_MEMORY_SCOPE_SYSTEM);
}

__device__ __forceinline__ float wave_reduce(float v) {
  #pragma unroll
  for (int o = 32; o > 0; o >>= 1) v += __shfl_down(v, o, 64);
  return v;
}

// Group-local barrier (32 blocks of one batch), verified R3-R6. Block j
// write-through-stores its monotone phase number into word j of the group's
// 128-B slot line; wave 0 polls with system-scope relaxed loads (always served
// from the coherence point -> cannot spin stale).
__device__ __forceinline__ void gbar(unsigned* slots, int g, int j, int t, unsigned phase) {
  __syncthreads();                        // drains vmcnt: stores + atomics acked
  if (t < 64) {
    if (t == 0)
      __hip_atomic_store(&slots[g * GSZ + j], phase, __ATOMIC_RELAXED, __HIP_MEMORY_SCOPE_SYSTEM);
    const unsigned* line = slots + g * GSZ;
    int sl = t & 31;
    for (;;) {
      unsigned v = __hip_atomic_load(&line[sl], __ATOMIC_RELAXED, __HIP_MEMORY_SCOPE_SYSTEM);
      if (__all((int)(v >= phase))) break;
      __builtin_amdgcn_s_sleep(2);
    }
  }
  __syncthreads();
}

// Wave-shuffle softmax: 3 __syncthreads (verified R5/R6).
__device__ void softmax257(float* l, float* red, int t) {
  int lane = t & 63, wv = t >> 6;
  float v = l[t];
  float v256 = l[256];
  float m = v;
  #pragma unroll
  for (int o = 32; o > 0; o >>= 1) m = fmaxf(m, __shfl_xor(m, o, 64));
  if (lane == 0) red[wv] = m;
  __syncthreads();
  float M = fmaxf(fmaxf(fmaxf(red[0], red[1]), fmaxf(red[2], red[3])), v256);
  float ex = expf(v - M);
  float e256 = expf(v256 - M);
  float s = ex;
  #pragma unroll
  for (int o = 32; o > 0; o >>= 1) s += __shfl_xor(s, o, 64);
  if (lane == 0) red[4 + wv] = s;
  __syncthreads();
  float inv = 1.f / (red[4] + red[5] + red[6] + red[7] + e256);
  l[t] = ex * inv;
  if (t == 0) l[256] = e256 * inv;
  __syncthreads();
}

__global__ __launch_bounds__(NTHR, 4) void k_mega(
    const float* __restrict__ xr, const float* __restrict__ xi,
    const float* __restrict__ pos_r, const float* __restrict__ pos_i,
    const float* __restrict__ w_in_r, const float* __restrict__ w_in_i,
    const float* __restrict__ b_in_r, const float* __restrict__ b_in_i,
    const float* __restrict__ w_out_r, const float* __restrict__ w_out_i,
    const float* __restrict__ b_out_r, const float* __restrict__ b_out_i,
    const float* __restrict__ w_p_r, const float* __restrict__ w_p_i,
    const float* __restrict__ b_p_r, const float* __restrict__ b_p_i,
    unsigned* slots,
    float* __restrict__ ur_, float* __restrict__ ui_,
    float* __restrict__ lgr, float* __restrict__ lgi,
    float* __restrict__ mr, float* __restrict__ mi,
    float* __restrict__ w2,
    float* __restrict__ zr_, float* __restrict__ zi_,
    float* __restrict__ a0r, float* __restrict__ a0i,
    float* __restrict__ aor, float* __restrict__ aoi,
    float* __restrict__ out, int interleaved) {
  __shared__ __align__(16) float smF[4112];   // max phase: P5's 2056 float2 = 16448 B
  const int t   = threadIdx.x;
  const int l   = t & 63;
  const int w   = t >> 6;
  const int bid = blockIdx.x;
  const int g   = bid >> 5;     // batch b (32 groups)
  const int j   = bid & 31;     // block within group

  // ---- P1: m[g,e] = mean_s x + pos[e,0]. Block j owns e rows [16j,16j+16). ----
  #pragma unroll
  for (int rr = 0; rr < 4; ++rr) {
    int e = j * 16 + w * 4 + rr;
    float4 vr = ((const float4*)(xr + ((size_t)g * E_ + e) * HW_))[l];
    float4 vi = ((const float4*)(xi + ((size_t)g * E_ + e) * HW_))[l];
    float sr = (vr.x + vr.y) + (vr.z + vr.w);
    float si = (vi.x + vi.y) + (vi.z + vi.w);
    sr = wave_reduce(sr); si = wave_reduce(si);
    if (l == 0) {
      st_sys(&mr[g * E_ + e], sr * (1.f / HW_) + pos_r[(size_t)e * S_]);
      st_sys(&mi[g * E_ + e], si * (1.f / HW_) + pos_i[(size_t)e * S_]);
    }
  }
  gbar(slots, g, j, t, 1);

  // ---- P2: q0 for this block's 16 f-rows (never leaves the block), then
  //      u[h,e] += sum_{own d} q0[d] * w_k[f,e] via coalesced w_k ROW reads +
  //      4-way atomicAdd. Eliminates the q0 round-trip AND P3's strided w_k gather. ----
  {
    float* mR  = smF;          // 512
    float* mI  = smF + 512;    // 512
    float* q0L = smF + 1024;   // 32 (16 f x {r,i})
    mR[t]       = mr[g * E_ + t];        mI[t]       = mi[g * E_ + t];
    mR[t + 256] = mr[g * E_ + t + 256];  mI[t + 256] = mi[g * E_ + t + 256];
    __syncthreads();
    #pragma unroll
    for (int rr = 0; rr < 4; ++rr) {
      int fl = w * 4 + rr;               // local f index 0..15
      int f  = 16 * j + fl;
      const float* wr = w_in_r + (size_t)f * E_;
      const float* wi = w_in_i + (size_t)f * E_;
      float ar = 0.f, ai = 0.f;
      #pragma unroll
      for (int e = l; e < E_; e += 64) {
        float Xr = mR[e], Xi = mI[e], Cr = wr[e], Ci = wi[e];
        ar += Xr * Cr - Xi * Ci;
        ai += Xr * Ci + Xi * Cr;
      }
      ar = wave_reduce(ar); ai = wave_reduce(ai);
      if (l == 0) {
        q0L[fl * 2]     = (ar + b_in_r[f]) * 0.125f;
        q0L[fl * 2 + 1] = (ai + b_in_i[f]) * 0.125f;
      }
    }
    __syncthreads();
    int h = j >> 2;                       // this block's head
    float u0r = 0.f, u0i = 0.f, u1r = 0.f, u1i = 0.f;
    #pragma unroll 4
    for (int fl = 0; fl < 16; ++fl) {
      int f = 16 * j + fl;
      float qr = q0L[fl * 2], qi = q0L[fl * 2 + 1];
      const float* Wr = w_in_r + (size_t)(E_ + f) * E_;
      const float* Wi = w_in_i + (size_t)(E_ + f) * E_;
      float W0r = Wr[t], W0i = Wi[t], W1r = Wr[t + 256], W1i = Wi[t + 256];
      u0r += qr * W0r - qi * W0i;  u0i += qr * W0i + qi * W0r;
      u1r += qr * W1r - qi * W1i;  u1i += qr * W1i + qi * W1r;
    }
    size_t ub = (size_t)(g * NH_ + h) * E_;
    atomicAdd(&ur_[ub + t], u0r);        atomicAdd(&ui_[ub + t], u0i);
    atomicAdd(&ur_[ub + t + 256], u1r);  atomicAdd(&ui_[ub + t + 256], u1i);
  }
  gbar(slots, g, j, t, 2);

  // ---- P3: partial logits for e-chunk [16j,16j+16) (same x rows as P1),
  //      atomicAdd straight into lgt[g,h,k] -- no 33MB part round-trip. ----
  {
    int e0 = 16 * j;
    float* us = smF;                     // [16][8][2] = 256 floats
    if (t < 128) {
      int e = t & 15, hh = t >> 4;
      us[(e * 8 + hh) * 2]     = ur_[(size_t)(g * NH_ + hh) * E_ + e0 + e];
      us[(e * 8 + hh) * 2 + 1] = ui_[(size_t)(g * NH_ + hh) * E_ + e0 + e];
    }
    __syncthreads();
    float ar[NH_], ai[NH_];
    #pragma unroll
    for (int hh = 0; hh < NH_; ++hh) { ar[hh] = 0.f; ai[hh] = 0.f; }
    const float* xrb = xr + ((size_t)g * E_ + e0) * HW_;
    const float* xib = xi + ((size_t)g * E_ + e0) * HW_;
    #pragma unroll 2
    for (int e = 0; e < 16; ++e) {
      float Xr = xrb[e * HW_ + t] + pos_r[(size_t)(e0 + e) * S_ + t + 1];
      float Xi = xib[e * HW_ + t] + pos_i[(size_t)(e0 + e) * S_ + t + 1];
      #pragma unroll
      for (int hh = 0; hh < NH_; ++hh) {
        float Ur = us[(e * 8 + hh) * 2], Ui = us[(e * 8 + hh) * 2 + 1];
        ar[hh] += Xr * Ur - Xi * Ui;
        ai[hh] += Xr * Ui + Xi * Ur;
      }
    }
    #pragma unroll
    for (int hh = 0; hh < NH_; ++hh) {
      size_t lb = (size_t)(g * NH_ + hh) * LG_ + t + 1;
      atomicAdd(&lgr[lb], ar[hh]);
      atomicAdd(&lgi[lb], ai[hh]);
    }
  }
  gbar(slots, g, j, t, 3);

  // ---- P4: blocks j<8 (head j): read lgt row + l0 = m.u + dual softmax.
  //      Idle blocks (j>=8) touch their P5 x rows to warm this XCD's L2. ----
  if (j < NH_) {
    int bh = g * NH_ + j;
    float* lr  = smF;          // 260
    float* li  = smF + 260;    // 260
    float* redl = smF + 520;   // 8 (l0 wave partials)
    float* reds = smF + 528;   // 8 (softmax scratch)
    lr[t + 1] = lgr[(size_t)bh * LG_ + t + 1];
    li[t + 1] = lgi[(size_t)bh * LG_ + t + 1];
    float pr = 0.f, pi = 0.f;
    #pragma unroll
    for (int e = t; e < E_; e += 256) {
      float Xr = mr[g * E_ + e], Xi = mi[g * E_ + e];
      float Ur = ur_[(size_t)bh * E_ + e], Ui = ui_[(size_t)bh * E_ + e];
      pr += Xr * Ur - Xi * Ui;
      pi += Xr * Ui + Xi * Ur;
    }
    pr = wave_reduce(pr); pi = wave_reduce(pi);
    if (l == 0) { redl[w * 2] = pr; redl[w * 2 + 1] = pi; }
    __syncthreads();
    if (t == 0) {
      lr[0] = redl[0] + redl[2] + redl[4] + redl[6];
      li[0] = redl[1] + redl[3] + redl[5] + redl[7];
    }
    __syncthreads();
    softmax257(lr, reds, t);
    softmax257(li, reds, t);
    float2* o = (float2*)w2 + (size_t)bh * S_;
    float2 v; v.x = lr[t]; v.y = li[t];
    st_sys2(&o[t], v);
    if (t == 0) { float2 v2; v2.x = lr[256]; v2.y = li[256]; st_sys2(&o[256], v2); }
  } else {
    // warm L2 with this block's P5 x rows (idle blocks only; off critical path)
    int idx = t & 127;
    int e = 16 * j + (idx & 15);
    const float* src = (t < 128) ? xr : xi;
    float pf = src[((size_t)g * E_ + e) * HW_ + (idx >> 4) * 32];
    asm volatile("" :: "v"(pf));
  }
  gbar(slots, g, j, t, 4);

  // ---- P5: z[g,h,e] = sum_k w[g,h,k] X[g,k,e]; block j owns e rows [16j,16j+16)
  //      (same x rows as P1/P3 -> MALL/L2-warm); w-tile in LDS. ----
  {
    float2* wls = (float2*)smF;                 // 2056 float2
    const float2* w2b = (const float2*)w2 + (size_t)g * NH_ * S_;
    for (int i = t; i < NH_ * S_; i += NTHR) wls[i] = w2b[i];
    __syncthreads();
    #pragma unroll
    for (int rr = 0; rr < 4; ++rr) {
      int e = 16 * j + 4 * w + rr;
      const float* xre = xr + ((size_t)g * E_ + e) * HW_;
      const float* xie = xi + ((size_t)g * E_ + e) * HW_;
      const float* pre = pos_r + (size_t)e * S_;
      const float* pie = pos_i + (size_t)e * S_;
      float ar2[NH_], ai2[NH_];
      #pragma unroll
      for (int hh = 0; hh < NH_; ++hh) { ar2[hh] = 0.f; ai2[hh] = 0.f; }
      #pragma unroll
      for (int jj = 0; jj < 4; ++jj) {
        int k = 1 + l + 64 * jj;
        float Xr = xre[k - 1] + pre[k];
        float Xi = xie[k - 1] + pie[k];
        #pragma unroll
        for (int hh = 0; hh < NH_; ++hh) {
          float2 W = wls[hh * S_ + k];
          ar2[hh] += W.x * Xr - W.y * Xi;
          ai2[hh] += W.x * Xi + W.y * Xr;
        }
      }
      #pragma unroll
      for (int hh = 0; hh < NH_; ++hh) { ar2[hh] = wave_reduce(ar2[hh]); ai2[hh] = wave_reduce(ai2[hh]); }
      if (l == 0) {
        float X0r = mr[g * E_ + e];
        float X0i = mi[g * E_ + e];
        #pragma unroll
        for (int hh = 0; hh < NH_; ++hh) {
          float2 W0 = wls[hh * S_];
          st_sys(&zr_[(size_t)(g * NH_ + hh) * E_ + e], ar2[hh] + W0.x * X0r - W0.y * X0i);
          st_sys(&zi_[(size_t)(g * NH_ + hh) * E_ + e], ai2[hh] + W0.x * X0i + W0.y * X0r);
        }
      }
    }
  }
  gbar(slots, g, j, t, 5);

  // ---- P6: a0[g,f] = w_v[f,:] . z[g,h(f),:] + b_v[f]*(1+i); block owns 16 f ----
  #pragma unroll
  for (int rr = 0; rr < 4; ++rr) {
    int f = j * 16 + w * 4 + rr;
    int h = f >> 6;
    const float* wrp = w_in_r + (size_t)(2 * E_ + f) * E_;
    const float* wip = w_in_i + (size_t)(2 * E_ + f) * E_;
    const float* zrp = zr_ + (size_t)(g * NH_ + h) * E_;
    const float* zip = zi_ + (size_t)(g * NH_ + h) * E_;
    float ar = 0.f, ai = 0.f;
    #pragma unroll
    for (int e = l; e < E_; e += 64) {
      float Zr = zrp[e], Zi = zip[e], Cr = wrp[e], Ci = wip[e];
      ar += Zr * Cr - Zi * Ci;
      ai += Zr * Ci + Zi * Cr;
    }
    ar = wave_reduce(ar); ai = wave_reduce(ai);
    if (l == 0) {
      float bvr = b_in_r[2 * E_ + f], bvi = b_in_i[2 * E_ + f];
      st_sys(&a0r[g * E_ + f], ar + (bvr - bvi));   // sum of complex softmax weights = 1+i
      st_sys(&a0i[g * E_ + f], ai + (bvr + bvi));
    }
  }
  gbar(slots, g, j, t, 6);

  // ---- P7: ao[g,f] = a0[g,:] . w_out[f,:] + b_out[f] ----
  #pragma unroll
  for (int rr = 0; rr < 4; ++rr) {
    int f = j * 16 + w * 4 + rr;
    const float* wrp = w_out_r + (size_t)f * E_;
    const float* wip = w_out_i + (size_t)f * E_;
    const float* ir = a0r + (size_t)g * E_;
    const float* ii = a0i + (size_t)g * E_;
    float ar = 0.f, ai = 0.f;
    #pragma unroll
    for (int e = l; e < E_; e += 64) {
      float Xr = ir[e], Xi = ii[e], Cr = wrp[e], Ci = wip[e];
      ar += Xr * Cr - Xi * Ci;
      ai += Xr * Ci + Xi * Cr;
    }
    ar = wave_reduce(ar); ai = wave_reduce(ai);
    if (l == 0) { st_sys(&aor[g * E_ + f], ar + b_out_r[f]); st_sys(&aoi[g * E_ + f], ai + b_out_i[f]); }
  }
  gbar(slots, g, j, t, 7);

  // ---- P8: final projection, interleaved complex64 out ----
  #pragma unroll
  for (int rr = 0; rr < 4; ++rr) {
    int f = j * 16 + w * 4 + rr;
    const float* wrp = w_p_r + (size_t)f * E_;
    const float* wip = w_p_i + (size_t)f * E_;
    const float* ir = aor + (size_t)g * E_;
    const float* ii = aoi + (size_t)g * E_;
    float ar = 0.f, ai = 0.f;
    #pragma unroll
    for (int e = l; e < E_; e += 64) {
      float Xr = ir[e], Xi = ii[e], Cr = wrp[e], Ci = wip[e];
      ar += Xr * Cr - Xi * Ci;
      ai += Xr * Ci + Xi * Cr;
    }
    ar = wave_reduce(ar); ai = wave_reduce(ai);
    if (l == 0) {
      float rr2 = ar + b_p_r[f];
      float im  = ai + b_p_i[f];
      int wid = g * E_ + f;
      if (interleaved) { out[(size_t)wid * 2] = rr2; out[(size_t)wid * 2 + 1] = im; }
      else             { out[wid] = rr2; }
    }
  }
}

extern "C" void kernel_launch(void* const* d_in, const int* in_sizes, int n_in,
                              void* d_out, int out_size, void* d_ws, size_t ws_size,
                              hipStream_t stream) {
  (void)in_sizes; (void)n_in; (void)ws_size;
  const float* xr      = (const float*)d_in[0];
  const float* xi      = (const float*)d_in[1];
  const float* pos_r   = (const float*)d_in[2];
  const float* pos_i   = (const float*)d_in[3];
  const float* w_in_r  = (const float*)d_in[4];
  const float* w_in_i  = (const float*)d_in[5];
  const float* b_in_r  = (const float*)d_in[6];
  const float* b_in_i  = (const float*)d_in[7];
  const float* w_out_r = (const float*)d_in[8];
  const float* w_out_i = (const float*)d_in[9];
  const float* b_out_r = (const float*)d_in[10];
  const float* b_out_i = (const float*)d_in[11];
  const float* w_p_r   = (const float*)d_in[12];
  const float* w_p_i   = (const float*)d_in[13];
  const float* b_p_r   = (const float*)d_in[14];
  const float* b_p_i   = (const float*)d_in[15];

  const int BE = B_ * E_, BHE = B_ * NH_ * E_;
  float* ws = (float*)d_ws;
  // ---- zeroed region (atomic accumulators + barrier slots), contiguous ----
  unsigned* slots = (unsigned*)d_ws;             // 1024 u32 = 4 KB
  float* ur   = ws + 1024;                       // B*NH*E = 131072
  float* ui   = ur + BHE;
  float* lgr  = ui + BHE;                        // B*NH*LG_ = 66560
  float* lgi  = lgr + B_ * NH_ * LG_;
  // ---- plain write-through region ----
  float* mr   = lgi + B_ * NH_ * LG_;
  float* mi   = mr + BE;
  float* w2   = mi + BE;                         // 2*B*NH*S = 133120
  float* zr   = w2 + (size_t)2 * B_ * NH_ * S_;
  float* zi   = zr + BHE;
  float* a0r  = zi + BHE;
  float* a0i  = a0r + BE;
  float* aor  = a0i + BE;
  float* aoi  = aor + BE;

  // Zero slots + u + lgt accumulators (1.59 MB). The memset's dispatch-end
  // writeback-invalidate also clears stale L2 lines before k_mega starts.
  size_t zbytes = (size_t)(1024 + 2 * BHE + 2 * B_ * NH_ * LG_) * 4;
  hipMemsetAsync(d_ws, 0, zbytes, stream);
  k_mega<<<NBLK, NTHR, 0, stream>>>(
      xr, xi, pos_r, pos_i, w_in_r, w_in_i, b_in_r, b_in_i,
      w_out_r, w_out_i, b_out_r, b_out_i, w_p_r, w_p_i, b_p_r, b_p_i,
      slots, ur, ui, lgr, lgi, mr, mi, w2, zr, zi, a0r, a0i, aor, aoi,
      (float*)d_out, out_size >= 2 * B_ * E_);
}

// Round 8
// 196.841 us; speedup vs baseline: 1.4450x; 1.0394x over previous
//
#include <hip/hip_runtime.h>

#define B_   32
#define E_   512
#define HW_  256
#define S_   257
#define NH_  8
#define NBLK 1024
#define NTHR 256
#define NGRP 32
#define GSZ  32
#define LG_  260   // padded logit row stride

// write-through stores (sc0 sc1): land at the coherence point (MALL). Intermediates
// are written once and first-read only after a barrier, so no reader L2 can hold
// a stale copy -> barriers need zero cache-maintenance ops (verified R3-R7).
__device__ __forceinline__ void st_sys(float* p, float v) {
  __hip_atomic_store(p, v, __ATOMIC_RELAXED, __HIP_MEMORY_SCOPE_SYSTEM);
}
__device__ __forceinline__ void st_sys2(float2* p, float2 v) {
  unsigned long long u;
  __builtin_memcpy(&u, &v, 8);
  __hip_atomic_store((unsigned long long*)p, u, __ATOMIC_RELAXED, __HIP_MEMORY_SCOPE_SYSTEM);
}

__device__ __forceinline__ float wave_reduce(float v) {
  #pragma unroll
  for (int o = 32; o > 0; o >>= 1) v += __shfl_down(v, o, 64);
  return v;
}

// Group-local barrier (32 blocks of one batch), verified R3-R7. Block j
// write-through-stores its monotone phase number into word j of the group's
// 128-B slot line; wave 0 polls with system-scope relaxed loads. s_sleep(8)
// backoff: 1024 pollers at ~350ns/poll were ~370 GB/s of parasitic MALL
// traffic competing with data; 4x backoff frees the coherence point.
__device__ __forceinline__ void gbar(unsigned* slots, int g, int j, int t, unsigned phase) {
  __syncthreads();                        // drains vmcnt: stores + atomics acked
  if (t < 64) {
    if (t == 0)
      __hip_atomic_store(&slots[g * GSZ + j], phase, __ATOMIC_RELAXED, __HIP_MEMORY_SCOPE_SYSTEM);
    const unsigned* line = slots + g * GSZ;
    int sl = t & 31;
    for (;;) {
      unsigned v = __hip_atomic_load(&line[sl], __ATOMIC_RELAXED, __HIP_MEMORY_SCOPE_SYSTEM);
      if (__all((int)(v >= phase))) break;
      __builtin_amdgcn_s_sleep(8);
    }
  }
  __syncthreads();
}

// Wave-shuffle softmax: 3 __syncthreads (verified R5-R7).
__device__ void softmax257(float* l, float* red, int t) {
  int lane = t & 63, wv = t >> 6;
  float v = l[t];
  float v256 = l[256];
  float m = v;
  #pragma unroll
  for (int o = 32; o > 0; o >>= 1) m = fmaxf(m, __shfl_xor(m, o, 64));
  if (lane == 0) red[wv] = m;
  __syncthreads();
  float M = fmaxf(fmaxf(fmaxf(red[0], red[1]), fmaxf(red[2], red[3])), v256);
  float ex = expf(v - M);
  float e256 = expf(v256 - M);
  float s = ex;
  #pragma unroll
  for (int o = 32; o > 0; o >>= 1) s += __shfl_xor(s, o, 64);
  if (lane == 0) red[4 + wv] = s;
  __syncthreads();
  float inv = 1.f / (red[4] + red[5] + red[6] + red[7] + e256);
  l[t] = ex * inv;
  if (t == 0) l[256] = e256 * inv;
  __syncthreads();
}

__global__ __launch_bounds__(NTHR, 4) void k_mega(
    const float* __restrict__ xr, const float* __restrict__ xi,
    const float* __restrict__ pos_r, const float* __restrict__ pos_i,
    const float* __restrict__ w_in_r, const float* __restrict__ w_in_i,
    const float* __restrict__ b_in_r, const float* __restrict__ b_in_i,
    const float* __restrict__ w_out_r, const float* __restrict__ w_out_i,
    const float* __restrict__ b_out_r, const float* __restrict__ b_out_i,
    const float* __restrict__ w_p_r, const float* __restrict__ w_p_i,
    const float* __restrict__ b_p_r, const float* __restrict__ b_p_i,
    unsigned* slots,
    float* __restrict__ ur_, float* __restrict__ ui_,
    float* __restrict__ lgr, float* __restrict__ lgi,
    float* __restrict__ a0r, float* __restrict__ a0i,
    float* __restrict__ mr, float* __restrict__ mi,
    float* __restrict__ w2,
    float* __restrict__ out, int interleaved) {
  __shared__ __align__(16) float smF[4368];   // P56: 2056 float2 wtile + 256 z = 17472 B
  const int t   = threadIdx.x;
  const int l   = t & 63;
  const int w   = t >> 6;
  const int bid = blockIdx.x;
  const int g   = bid >> 5;     // batch b (32 groups)
  const int j   = bid & 31;     // block within group

  // ---- P1: m[g,e] = mean_s x + pos[e,0]. Block j owns e rows [16j,16j+16). ----
  #pragma unroll
  for (int rr = 0; rr < 4; ++rr) {
    int e = j * 16 + w * 4 + rr;
    float4 vr = ((const float4*)(xr + ((size_t)g * E_ + e) * HW_))[l];
    float4 vi = ((const float4*)(xi + ((size_t)g * E_ + e) * HW_))[l];
    float sr = (vr.x + vr.y) + (vr.z + vr.w);
    float si = (vi.x + vi.y) + (vi.z + vi.w);
    sr = wave_reduce(sr); si = wave_reduce(si);
    if (l == 0) {
      st_sys(&mr[g * E_ + e], sr * (1.f / HW_) + pos_r[(size_t)e * S_]);
      st_sys(&mi[g * E_ + e], si * (1.f / HW_) + pos_i[(size_t)e * S_]);
    }
  }
  gbar(slots, g, j, t, 1);

  // ---- P2: q0 for this block's 16 f-rows (block-local), then u[h,e] partial
  //      via coalesced w_k ROW reads + 4-way atomicAdd (verified R7). ----
  {
    float* mR  = smF;          // 512
    float* mI  = smF + 512;    // 512
    float* q0L = smF + 1024;   // 32 (16 f x {r,i})
    mR[t]       = mr[g * E_ + t];        mI[t]       = mi[g * E_ + t];
    mR[t + 256] = mr[g * E_ + t + 256];  mI[t + 256] = mi[g * E_ + t + 256];
    __syncthreads();
    #pragma unroll
    for (int rr = 0; rr < 4; ++rr) {
      int fl = w * 4 + rr;               // local f index 0..15
      int f  = 16 * j + fl;
      const float* wr = w_in_r + (size_t)f * E_;
      const float* wi = w_in_i + (size_t)f * E_;
      float ar = 0.f, ai = 0.f;
      #pragma unroll
      for (int e = l; e < E_; e += 64) {
        float Xr = mR[e], Xi = mI[e], Cr = wr[e], Ci = wi[e];
        ar += Xr * Cr - Xi * Ci;
        ai += Xr * Ci + Xi * Cr;
      }
      ar = wave_reduce(ar); ai = wave_reduce(ai);
      if (l == 0) {
        q0L[fl * 2]     = (ar + b_in_r[f]) * 0.125f;
        q0L[fl * 2 + 1] = (ai + b_in_i[f]) * 0.125f;
      }
    }
    __syncthreads();
    int h = j >> 2;                       // this block's head
    float u0r = 0.f, u0i = 0.f, u1r = 0.f, u1i = 0.f;
    #pragma unroll 4
    for (int fl = 0; fl < 16; ++fl) {
      int f = 16 * j + fl;
      float qr = q0L[fl * 2], qi = q0L[fl * 2 + 1];
      const float* Wr = w_in_r + (size_t)(E_ + f) * E_;
      const float* Wi = w_in_i + (size_t)(E_ + f) * E_;
      float W0r = Wr[t], W0i = Wi[t], W1r = Wr[t + 256], W1i = Wi[t + 256];
      u0r += qr * W0r - qi * W0i;  u0i += qr * W0i + qi * W0r;
      u1r += qr * W1r - qi * W1i;  u1i += qr * W1i + qi * W1r;
    }
    size_t ub = (size_t)(g * NH_ + h) * E_;
    atomicAdd(&ur_[ub + t], u0r);        atomicAdd(&ui_[ub + t], u0i);
    atomicAdd(&ur_[ub + t + 256], u1r);  atomicAdd(&ui_[ub + t + 256], u1i);
  }
  gbar(slots, g, j, t, 2);

  // ---- P3: partial logits for e-chunk [16j,16j+16) (same x rows as P1),
  //      atomicAdd straight into lgt[g,h,k] (verified R7). ----
  {
    int e0 = 16 * j;
    float* us = smF;                     // [16][8][2] = 256 floats
    if (t < 128) {
      int e = t & 15, hh = t >> 4;
      us[(e * 8 + hh) * 2]     = ur_[(size_t)(g * NH_ + hh) * E_ + e0 + e];
      us[(e * 8 + hh) * 2 + 1] = ui_[(size_t)(g * NH_ + hh) * E_ + e0 + e];
    }
    __syncthreads();
    float ar[NH_], ai[NH_];
    #pragma unroll
    for (int hh = 0; hh < NH_; ++hh) { ar[hh] = 0.f; ai[hh] = 0.f; }
    const float* xrb = xr + ((size_t)g * E_ + e0) * HW_;
    const float* xib = xi + ((size_t)g * E_ + e0) * HW_;
    #pragma unroll 2
    for (int e = 0; e < 16; ++e) {
      float Xr = xrb[e * HW_ + t] + pos_r[(size_t)(e0 + e) * S_ + t + 1];
      float Xi = xib[e * HW_ + t] + pos_i[(size_t)(e0 + e) * S_ + t + 1];
      #pragma unroll
      for (int hh = 0; hh < NH_; ++hh) {
        float Ur = us[(e * 8 + hh) * 2], Ui = us[(e * 8 + hh) * 2 + 1];
        ar[hh] += Xr * Ur - Xi * Ui;
        ai[hh] += Xr * Ui + Xi * Ur;
      }
    }
    #pragma unroll
    for (int hh = 0; hh < NH_; ++hh) {
      size_t lb = (size_t)(g * NH_ + hh) * LG_ + t + 1;
      atomicAdd(&lgr[lb], ar[hh]);
      atomicAdd(&lgi[lb], ai[hh]);
    }
  }
  gbar(slots, g, j, t, 3);

  // ---- P4: blocks j<8 (head j): lgt row + l0 = m.u + dual softmax.
  //      Idle blocks warm this XCD's L2 with their P56 x rows. ----
  if (j < NH_) {
    int bh = g * NH_ + j;
    float* lr  = smF;          // 260
    float* li  = smF + 260;    // 260
    float* redl = smF + 520;   // 8 (l0 wave partials)
    float* reds = smF + 528;   // 8 (softmax scratch)
    lr[t + 1] = lgr[(size_t)bh * LG_ + t + 1];
    li[t + 1] = lgi[(size_t)bh * LG_ + t + 1];
    float pr = 0.f, pi = 0.f;
    #pragma unroll
    for (int e = t; e < E_; e += 256) {
      float Xr = mr[g * E_ + e], Xi = mi[g * E_ + e];
      float Ur = ur_[(size_t)bh * E_ + e], Ui = ui_[(size_t)bh * E_ + e];
      pr += Xr * Ur - Xi * Ui;
      pi += Xr * Ui + Xi * Ur;
    }
    pr = wave_reduce(pr); pi = wave_reduce(pi);
    if (l == 0) { redl[w * 2] = pr; redl[w * 2 + 1] = pi; }
    __syncthreads();
    if (t == 0) {
      lr[0] = redl[0] + redl[2] + redl[4] + redl[6];
      li[0] = redl[1] + redl[3] + redl[5] + redl[7];
    }
    __syncthreads();
    softmax257(lr, reds, t);
    softmax257(li, reds, t);
    float2* o = (float2*)w2 + (size_t)bh * S_;
    float2 v; v.x = lr[t]; v.y = li[t];
    st_sys2(&o[t], v);
    if (t == 0) { float2 v2; v2.x = lr[256]; v2.y = li[256]; st_sys2(&o[256], v2); }
  } else {
    int idx = t & 127;
    int e = 16 * j + (idx & 15);
    const float* src = (t < 128) ? xr : xi;
    float pf = src[((size_t)g * E_ + e) * HW_ + (idx >> 4) * 32];
    asm volatile("" :: "v"(pf));
  }
  gbar(slots, g, j, t, 4);

  // ---- P56 (merged): z[h, e-slice] -> LDS only, then a0[f] partial =
  //      sum_{e in slice} w_v[f,e] * z[h(f),e], atomicAdd into zeroed a0.
  //      Kills the z round-trip, the cross-block z gather, and one barrier. ----
  {
    float2* wls = (float2*)smF;                 // 2056 float2 = 16448 B
    float*  zS  = smF + 4112;                   // [h][el]{r,i} = 256 floats
    const float2* w2b = (const float2*)w2 + (size_t)g * NH_ * S_;
    for (int i = t; i < NH_ * S_; i += NTHR) wls[i] = w2b[i];
    __syncthreads();
    #pragma unroll
    for (int rr = 0; rr < 4; ++rr) {
      int el = 4 * w + rr;
      int e  = 16 * j + el;                     // same x rows as P1/P3 -> warm
      const float* xre = xr + ((size_t)g * E_ + e) * HW_;
      const float* xie = xi + ((size_t)g * E_ + e) * HW_;
      const float* pre = pos_r + (size_t)e * S_;
      const float* pie = pos_i + (size_t)e * S_;
      float ar2[NH_], ai2[NH_];
      #pragma unroll
      for (int hh = 0; hh < NH_; ++hh) { ar2[hh] = 0.f; ai2[hh] = 0.f; }
      #pragma unroll
      for (int jj = 0; jj < 4; ++jj) {
        int k = 1 + l + 64 * jj;
        float Xr = xre[k - 1] + pre[k];
        float Xi = xie[k - 1] + pie[k];
        #pragma unroll
        for (int hh = 0; hh < NH_; ++hh) {
          float2 W = wls[hh * S_ + k];
          ar2[hh] += W.x * Xr - W.y * Xi;
          ai2[hh] += W.x * Xi + W.y * Xr;
        }
      }
      #pragma unroll
      for (int hh = 0; hh < NH_; ++hh) { ar2[hh] = wave_reduce(ar2[hh]); ai2[hh] = wave_reduce(ai2[hh]); }
      if (l == 0) {
        float X0r = mr[g * E_ + e];
        float X0i = mi[g * E_ + e];
        #pragma unroll
        for (int hh = 0; hh < NH_; ++hh) {
          float2 W0 = wls[hh * S_];
          zS[(hh * 16 + el) * 2]     = ar2[hh] + W0.x * X0r - W0.y * X0i;
          zS[(hh * 16 + el) * 2 + 1] = ai2[hh] + W0.x * X0i + W0.y * X0r;
        }
      }
    }
    __syncthreads();
    #pragma unroll
    for (int ff = 0; ff < 2; ++ff) {
      int f  = t + ff * 256;
      int hh = f >> 6;
      const float* wvr = w_in_r + (size_t)(2 * E_ + f) * E_ + 16 * j;
      const float* wvi = w_in_i + (size_t)(2 * E_ + f) * E_ + 16 * j;
      float cr = 0.f, ci = 0.f;
      #pragma unroll
      for (int el = 0; el < 16; ++el) {
        float Wr = wvr[el], Wi = wvi[el];
        float Zr = zS[(hh * 16 + el) * 2], Zi = zS[(hh * 16 + el) * 2 + 1];
        cr += Wr * Zr - Wi * Zi;
        ci += Wr * Zi + Wi * Zr;
      }
      if (j == 0) {                       // b_v*(1+i): sum of complex softmax = 1+i
        float bvr = b_in_r[2 * E_ + f], bvi = b_in_i[2 * E_ + f];
        cr += bvr - bvi;
        ci += bvr + bvi;
      }
      atomicAdd(&a0r[g * E_ + f], cr);
      atomicAdd(&a0i[g * E_ + f], ci);
    }
  }
  gbar(slots, g, j, t, 5);

  // ---- P78 (merged): ao for this block's 16 f' (incl. b_out), then rank-16
  //      contribution to out[o] = sum_{f'} ao[f'] w_p[o,f'] via atomicAdd into
  //      the zeroed output. b_p added by block 0. Kills the ao round-trip + barrier. ----
  {
    float* aoS = smF;          // 32
    float* a0R = smF + 64;     // 512
    float* a0I = smF + 576;    // 512
    a0R[t]       = a0r[g * E_ + t];        a0I[t]       = a0i[g * E_ + t];
    a0R[t + 256] = a0r[g * E_ + t + 256];  a0I[t + 256] = a0i[g * E_ + t + 256];
    __syncthreads();
    #pragma unroll
    for (int rr = 0; rr < 4; ++rr) {
      int fl = w * 4 + rr;
      int f  = 16 * j + fl;
      const float* wrp = w_out_r + (size_t)f * E_;
      const float* wip = w_out_i + (size_t)f * E_;
      float ar = 0.f, ai = 0.f;
      #pragma unroll
      for (int e = l; e < E_; e += 64) {
        float Xr = a0R[e], Xi = a0I[e], Cr = wrp[e], Ci = wip[e];
        ar += Xr * Cr - Xi * Ci;
        ai += Xr * Ci + Xi * Cr;
      }
      ar = wave_reduce(ar); ai = wave_reduce(ai);
      if (l == 0) { aoS[fl * 2] = ar + b_out_r[f]; aoS[fl * 2 + 1] = ai + b_out_i[f]; }
    }
    __syncthreads();
    #pragma unroll
    for (int ff = 0; ff < 2; ++ff) {
      int o = t + ff * 256;
      const float* wpr = w_p_r + (size_t)o * E_ + 16 * j;
      const float* wpi = w_p_i + (size_t)o * E_ + 16 * j;
      float cr = 0.f, ci = 0.f;
      #pragma unroll
      for (int fl = 0; fl < 16; ++fl) {
        float Ar = aoS[fl * 2], Ai = aoS[fl * 2 + 1];
        float Wr = wpr[fl],     Wi = wpi[fl];
        cr += Ar * Wr - Ai * Wi;
        ci += Ar * Wi + Ai * Wr;
      }
      if (j == 0) { cr += b_p_r[o]; ci += b_p_i[o]; }
      int wid = g * E_ + o;
      if (interleaved) {
        atomicAdd(&out[(size_t)wid * 2],     cr);
        atomicAdd(&out[(size_t)wid * 2 + 1], ci);
      } else {
        atomicAdd(&out[wid], cr);
      }
    }
  }
}

extern "C" void kernel_launch(void* const* d_in, const int* in_sizes, int n_in,
                              void* d_out, int out_size, void* d_ws, size_t ws_size,
                              hipStream_t stream) {
  (void)in_sizes; (void)n_in; (void)ws_size;
  const float* xr      = (const float*)d_in[0];
  const float* xi      = (const float*)d_in[1];
  const float* pos_r   = (const float*)d_in[2];
  const float* pos_i   = (const float*)d_in[3];
  const float* w_in_r  = (const float*)d_in[4];
  const float* w_in_i  = (const float*)d_in[5];
  const float* b_in_r  = (const float*)d_in[6];
  const float* b_in_i  = (const float*)d_in[7];
  const float* w_out_r = (const float*)d_in[8];
  const float* w_out_i = (const float*)d_in[9];
  const float* b_out_r = (const float*)d_in[10];
  const float* b_out_i = (const float*)d_in[11];
  const float* w_p_r   = (const float*)d_in[12];
  const float* w_p_i   = (const float*)d_in[13];
  const float* b_p_r   = (const float*)d_in[14];
  const float* b_p_i   = (const float*)d_in[15];

  const int BE = B_ * E_, BHE = B_ * NH_ * E_;
  float* ws = (float*)d_ws;
  // ---- zeroed region (barrier slots + all atomic accumulators), contiguous ----
  unsigned* slots = (unsigned*)d_ws;             // 1024 u32 = 4 KB
  float* ur   = ws + 1024;                       // B*NH*E = 131072
  float* ui   = ur + BHE;
  float* lgr  = ui + BHE;                        // B*NH*LG_ = 66560
  float* lgi  = lgr + B_ * NH_ * LG_;
  float* a0r  = lgi + B_ * NH_ * LG_;            // B*E
  float* a0i  = a0r + BE;
  // ---- plain write-through region ----
  float* mr   = a0i + BE;
  float* mi   = mr + BE;
  float* w2   = mi + BE;                         // 2*B*NH*S

  int interleaved = out_size >= 2 * B_ * E_;

  // Zero slots + u + lgt + a0 accumulators (~1.7 MB) and the output buffer
  // (out is atomically accumulated now). Dispatch-end writeback-invalidates
  // also clear stale L2 lines before k_mega starts.
  size_t zbytes = (size_t)(1024 + 2 * BHE + 2 * B_ * NH_ * LG_ + 2 * BE) * 4;
  hipMemsetAsync(d_ws, 0, zbytes, stream);
  hipMemsetAsync(d_out, 0, (size_t)(interleaved ? 2 * BE : BE) * 4, stream);
  k_mega<<<NBLK, NTHR, 0, stream>>>(
      xr, xi, pos_r, pos_i, w_in_r, w_in_i, b_in_r, b_in_i,
      w_out_r, w_out_i, b_out_r, b_out_i, w_p_r, w_p_i, b_p_r, b_p_i,
      slots, ur, ui, lgr, lgi, a0r, a0i, mr, mi, w2,
      (float*)d_out, interleaved);
}